// Round 3
// baseline (877.760 us; speedup 1.0000x reference)
//
#include <hip/hip_runtime.h>
#include <cstdint>
#include <cstddef>

// Problem constants (from reference setup_inputs)
#define B_     4
#define N_     4096
#define C_     768
#define HEADS_ 12
#define PTS_   4
#define HD_    64
#define HID_   3072
#define HH_    64
#define WW_    64

typedef unsigned short u16;
typedef __bf16 bf16x8 __attribute__((ext_vector_type(8)));
typedef float  f32x4  __attribute__((ext_vector_type(4)));
typedef unsigned short ushort8 __attribute__((ext_vector_type(8)));

__device__ __forceinline__ float b2f(u16 x) {
    union { unsigned int u; float f; } v; v.u = ((unsigned int)x) << 16; return v.f;
}
__device__ __forceinline__ u16 f2bf(float f) {
    union { float f; unsigned int u; } v; v.f = f;
    unsigned int u = v.u;
    u = u + 0x7fffu + ((u >> 16) & 1u);   // RNE
    return (u16)(u >> 16);
}

// ---------------------------------------------------------------------------
// Runtime dtype detection: norm1_w is all-ones. fp32 1.0f -> u16[0]=0x0000;
// bf16 1.0 -> u16[0]=0x3F80. flag: 0 = fp32 inputs, 1 = bf16 inputs.
// ---------------------------------------------------------------------------
__global__ void flag_k(const u16* __restrict__ n1w, int* __restrict__ flag) {
    if (threadIdx.x == 0) flag[0] = (n1w[0] == 0x3F80u) ? 1 : 0;
}

// ---------------------------------------------------------------------------
// Convert all weights/biases to bf16 in workspace (copy if already bf16).
// Segment layout (element offsets within dst):
//   qkvw 0..1769472, projw ..2359296, fc1w ..4718592, fc2w ..7077888,
//   offw ..7151616, qkvb ..7153920, projb ..7154688, fc1b ..7157760,
//   fc2b ..7158528, offb ..7158624, n1w ..7159392, n1b ..7160160,
//   n2w ..7160928, n2b ..7161696
// ---------------------------------------------------------------------------
template <int WANT, typename T>
__global__ __launch_bounds__(256) void convert_k(
    const int* __restrict__ flag,
    const void* qkvw, const void* projw, const void* fc1w, const void* fc2w,
    const void* offw, const void* qkvb, const void* projb, const void* fc1b,
    const void* fc2b, const void* offb, const void* n1w, const void* n1b,
    const void* n2w, const void* n2b,
    u16* __restrict__ dst)
{
    if (*flag != WANT) return;
    const int total = 7161696;
    for (int i = (int)blockIdx.x * 256 + (int)threadIdx.x; i < total; i += (int)gridDim.x * 256) {
        const void* src; int off;
        if      (i < 1769472) { src = qkvw; off = i; }
        else if (i < 2359296) { src = projw; off = i - 1769472; }
        else if (i < 4718592) { src = fc1w;  off = i - 2359296; }
        else if (i < 7077888) { src = fc2w;  off = i - 4718592; }
        else if (i < 7151616) { src = offw;  off = i - 7077888; }
        else if (i < 7153920) { src = qkvb;  off = i - 7151616; }
        else if (i < 7154688) { src = projb; off = i - 7153920; }
        else if (i < 7157760) { src = fc1b;  off = i - 7154688; }
        else if (i < 7158528) { src = fc2b;  off = i - 7157760; }
        else if (i < 7158624) { src = offb;  off = i - 7158528; }
        else if (i < 7159392) { src = n1w;   off = i - 7158624; }
        else if (i < 7160160) { src = n1b;   off = i - 7159392; }
        else if (i < 7160928) { src = n2w;   off = i - 7160160; }
        else                  { src = n2b;   off = i - 7160928; }
        if constexpr (sizeof(T) == 4) dst[i] = f2bf(((const float*)src)[off]);
        else                          dst[i] = ((const u16*)src)[off];
    }
}

// ---------------------------------------------------------------------------
// GEMM: out[M,N] = epilogue(A[M,K(lda)] @ Bw[N,K]^T + bias[N])
// A always bf16 (ws intermediate). Bw/bias always bf16 (converted).
// EPI: 0 = bias -> bf16; 1 = bias + exact gelu -> bf16;
//      2 = bias + resid(TRES) -> TOUT
// WANT: -1 = unguarded; else run only when *flag == WANT.
// Tile: 128x128x32, 4 waves, each wave 64x64 via 4x4 of 16x16x32 MFMA.
// ---------------------------------------------------------------------------
#define BM 128
#define BN 128
#define BK 32

template <int EPI, int WANT, typename TRES, typename TOUT>
__global__ __launch_bounds__(256) void gemm_nt(
    const int* __restrict__ flag,
    const u16* __restrict__ A, int lda,
    const u16* __restrict__ Bw,
    const u16* __restrict__ bias,
    const void* __restrict__ resid,
    void* __restrict__ outv,
    int M, int N, int K)
{
    if constexpr (WANT >= 0) { if (*flag != WANT) return; }

    __shared__ alignas(16) u16 As[BM * BK];   // 8 KB
    __shared__ alignas(16) u16 Bs[BN * BK];   // 8 KB

    const int tid  = (int)threadIdx.x;
    const int wid  = tid >> 6;
    const int lane = tid & 63;
    const int l15  = lane & 15;
    const int quad = lane >> 4;
    const int m0   = (int)blockIdx.y * BM;
    const int n0   = (int)blockIdx.x * BN;
    const int wm   = (wid & 1) * 64;
    const int wn   = (wid >> 1) * 64;

    const f32x4 zero4 = {0.f, 0.f, 0.f, 0.f};
    f32x4 acc[4][4];
#pragma unroll
    for (int i = 0; i < 4; i++)
#pragma unroll
        for (int j = 0; j < 4; j++) acc[i][j] = zero4;

    // staging granules: 512 x 16B per tile, 2 per thread
    const int g0 = tid, g1 = tid + 256;
    const int ar0 = g0 >> 2, ac0 = (g0 & 3) * 8;
    const int ar1 = g1 >> 2, ac1 = (g1 & 3) * 8;

    for (int k0 = 0; k0 < K; k0 += BK) {
        ushort8 a0 = *(const ushort8*)(A + (size_t)(m0 + ar0) * lda + k0 + ac0);
        ushort8 a1 = *(const ushort8*)(A + (size_t)(m0 + ar1) * lda + k0 + ac1);
        int br0 = n0 + ar0; if (br0 > N - 1) br0 = N - 1;
        int br1 = n0 + ar1; if (br1 > N - 1) br1 = N - 1;
        ushort8 b0 = *(const ushort8*)(Bw + (size_t)br0 * K + k0 + ac0);
        ushort8 b1 = *(const ushort8*)(Bw + (size_t)br1 * K + k0 + ac1);

        __syncthreads();
        ((ushort8*)As)[g0] = a0;
        ((ushort8*)As)[g1] = a1;
        ((ushort8*)Bs)[g0] = b0;
        ((ushort8*)Bs)[g1] = b1;
        __syncthreads();

        bf16x8 af[4], bfr[4];
#pragma unroll
        for (int i = 0; i < 4; i++)
            af[i] = *(const bf16x8*)(As + (wm + i * 16 + l15) * BK + quad * 8);
#pragma unroll
        for (int j = 0; j < 4; j++)
            bfr[j] = *(const bf16x8*)(Bs + (wn + j * 16 + l15) * BK + quad * 8);
#pragma unroll
        for (int i = 0; i < 4; i++)
#pragma unroll
            for (int j = 0; j < 4; j++)
                acc[i][j] = __builtin_amdgcn_mfma_f32_16x16x32_bf16(af[i], bfr[j], acc[i][j], 0, 0, 0);
    }

    // epilogue: reg r of acc[i][j] -> C[m0+wm+i*16+quad*4+r][n0+wn+j*16+l15]
#pragma unroll
    for (int j = 0; j < 4; j++) {
        int ncol = n0 + wn + j * 16 + l15;
        if (ncol >= N) continue;
        float bb = b2f(bias[ncol]);
#pragma unroll
        for (int i = 0; i < 4; i++) {
            int mbase = m0 + wm + i * 16 + quad * 4;
#pragma unroll
            for (int r = 0; r < 4; r++) {
                int m = mbase + r;
                float v = acc[i][j][r] + bb;
                size_t idx = (size_t)m * N + ncol;
                if (EPI == 0) {
                    ((u16*)outv)[idx] = f2bf(v);
                } else if (EPI == 1) {
                    float g = 0.5f * v * (1.0f + erff(v * 0.70710678118654752f));
                    ((u16*)outv)[idx] = f2bf(g);
                } else {
                    float res = (sizeof(TRES) == 4) ? ((const float*)resid)[idx]
                                                    : b2f(((const u16*)resid)[idx]);
                    float o = v + res;
                    if (sizeof(TOUT) == 4) ((float*)outv)[idx] = o;
                    else                   ((u16*)outv)[idx]   = f2bf(o);
                }
            }
        }
    }
}

// ---------------------------------------------------------------------------
// LayerNorm over last dim (768). One block (256 thr) per row. Output bf16.
// TIN = float or u16 input. w/b always bf16 (converted).
// ---------------------------------------------------------------------------
template <int WANT, typename TIN>
__global__ __launch_bounds__(256) void layernorm_k(
    const int* __restrict__ flag,
    const void* __restrict__ xin,
    const u16* __restrict__ w,
    const u16* __restrict__ bb,
    u16* __restrict__ out)
{
    if constexpr (WANT >= 0) { if (*flag != WANT) return; }
    const int row = (int)blockIdx.x;
    const int tid = (int)threadIdx.x;
    float v[3];
    float s = 0.f, s2 = 0.f;
#pragma unroll
    for (int i = 0; i < 3; i++) {
        int c = tid + i * 256;
        float t = (sizeof(TIN) == 4) ? ((const float*)xin)[(size_t)row * C_ + c]
                                     : b2f(((const u16*)xin)[(size_t)row * C_ + c]);
        v[i] = t; s += t; s2 += t * t;
    }
#pragma unroll
    for (int o = 32; o > 0; o >>= 1) { s += __shfl_xor(s, o); s2 += __shfl_xor(s2, o); }
    __shared__ float red[8];
    const int wid = tid >> 6, lane = tid & 63;
    if (lane == 0) { red[wid] = s; red[4 + wid] = s2; }
    __syncthreads();
    s  = red[0] + red[1] + red[2] + red[3];
    s2 = red[4] + red[5] + red[6] + red[7];
    const float mean = s * (1.0f / C_);
    float var = s2 * (1.0f / C_) - mean * mean;
    const float rstd = rsqrtf(var + 1e-5f);
#pragma unroll
    for (int i = 0; i < 3; i++) {
        int c = tid + i * 256;
        float o_ = (v[i] - mean) * rstd * b2f(w[c]) + b2f(bb[c]);
        out[(size_t)row * C_ + c] = f2bf(o_);
    }
}

// ---------------------------------------------------------------------------
// Deformable sampling + attention. One wave per (b, head, n); lane = channel d.
// qkv: [B*N, 3C] bf16. off: [B*N, 96] bf16. refp: [B*N, 2] in TR. out bf16.
// px = rx*W + ox - 0.5 ; py = ry*H + oy - 0.5 (algebraic reduction of
// loc=2*(ref+off/norm)-1 followed by grid_sample's unnormalize).
// ---------------------------------------------------------------------------
template <int WANT, typename TR>
__global__ __launch_bounds__(256) void deform_attn(
    const int* __restrict__ flag,
    const u16* __restrict__ qkv,
    const u16* __restrict__ off,
    const void* __restrict__ refp,
    u16* __restrict__ out)
{
    if constexpr (WANT >= 0) { if (*flag != WANT) return; }
    const int tid  = (int)threadIdx.x;
    const int wid  = tid >> 6;
    const int lane = tid & 63;
    const int wav  = (int)blockIdx.x * 4 + wid;      // 0 .. B*N*HEADS-1
    const int h    = wav % HEADS_;
    const int bn   = wav / HEADS_;                   // b*N + n
    const int b    = bn >> 12;                       // / N_ (4096)

    const float qd = b2f(qkv[(size_t)bn * (3 * C_) + h * HD_ + lane]);
    float rx, ry;
    if constexpr (sizeof(TR) == 4) {
        rx = ((const float*)refp)[(size_t)bn * 2 + 0];
        ry = ((const float*)refp)[(size_t)bn * 2 + 1];
    } else {
        rx = b2f(((const u16*)refp)[(size_t)bn * 2 + 0]);
        ry = b2f(((const u16*)refp)[(size_t)bn * 2 + 1]);
    }
    const int kchan = C_ + h * HD_ + lane;
    const size_t obase = (size_t)bn * (HEADS_ * PTS_ * 2) + h * (PTS_ * 2);

    float logit[PTS_], svd[PTS_];
#pragma unroll
    for (int p = 0; p < PTS_; p++) {
        const float ox = b2f(off[obase + p * 2 + 0]);
        const float oy = b2f(off[obase + p * 2 + 1]);
        float px = rx * (float)WW_ + ox - 0.5f;
        float py = ry * (float)HH_ + oy - 0.5f;
        px = fminf(fmaxf(px, -8.f), 72.f);   // NaN/garbage-proof
        py = fminf(fmaxf(py, -8.f), 72.f);
        const float x0f = floorf(px), y0f = floorf(py);
        const int x0 = (int)x0f, y0 = (int)y0f;
        const float wx = px - x0f, wy = py - y0f;
        float sk = 0.f, sv = 0.f;
#pragma unroll
        for (int c = 0; c < 4; c++) {
            const int xi = x0 + (c & 1);
            const int yi = y0 + (c >> 1);
            const float wgt = ((c & 1) ? wx : 1.f - wx) * ((c >> 1) ? wy : 1.f - wy);
            if (xi >= 0 && xi < WW_ && yi >= 0 && yi < HH_) {
                const size_t a = ((size_t)b * N_ + (yi * WW_ + xi)) * (3 * C_) + kchan;
                sk += wgt * b2f(qkv[a]);
                sv += wgt * b2f(qkv[a + C_]);
            }
        }
        logit[p] = qd * sk;
        svd[p]   = sv;
    }
#pragma unroll
    for (int p = 0; p < PTS_; p++)
#pragma unroll
        for (int o = 32; o > 0; o >>= 1) logit[p] += __shfl_xor(logit[p], o);

    const float scale = 0.125f;  // HD^-0.5
    float l0 = logit[0] * scale, l1 = logit[1] * scale, l2 = logit[2] * scale, l3 = logit[3] * scale;
    float mx = fmaxf(fmaxf(l0, l1), fmaxf(l2, l3));
    float e0 = expf(l0 - mx), e1 = expf(l1 - mx), e2 = expf(l2 - mx), e3 = expf(l3 - mx);
    float Z = e0 + e1 + e2 + e3;
    float od = (e0 * svd[0] + e1 * svd[1] + e2 * svd[2] + e3 * svd[3]) / Z;
    out[(size_t)bn * C_ + h * HD_ + lane] = f2bf(od);
}

// ---------------------------------------------------------------------------
extern "C" void kernel_launch(void* const* d_in, const int* in_sizes, int n_in,
                              void* d_out, int out_size, void* d_ws, size_t ws_size,
                              hipStream_t stream)
{
    const void* x     = d_in[0];
    const void* refp  = d_in[1];
    const void* n1w   = d_in[2];
    const void* n1b   = d_in[3];
    const void* qkvw  = d_in[4];
    const void* qkvb  = d_in[5];
    const void* offw  = d_in[6];
    const void* offb  = d_in[7];
    const void* projw = d_in[8];
    const void* projb = d_in[9];
    const void* n2w   = d_in[10];
    const void* n2b   = d_in[11];
    const void* fc1w  = d_in[12];
    const void* fc1b  = d_in[13];
    const void* fc2w  = d_in[14];
    const void* fc2b  = d_in[15];
    (void)in_sizes; (void)n_in; (void)out_size; (void)ws_size;

    const int M = B_ * N_;  // 16384

    // Workspace layout — peak 118,132,420 B:
    //   A [0,         25165824): h (s1-2) -> aout (s4-5) -> h2 (s6-7)
    //   B [25165824, 100663296): qkv (s2-4) -> x1 [25.1M,50.3M) + mbuf [50.3M,100.66M)
    //   C [100663296,103809024): offo (s3-4)
    //   D [103809024,118132416): converted weights/biases (bf16)
    //   E [118132416,118132420): dtype flag (int)
    char* ws = (char*)d_ws;
    u16* h    = (u16*)(ws);
    u16* aout = (u16*)(ws);
    u16* h2   = (u16*)(ws);
    u16* qkv  = (u16*)(ws + 25165824);
    u16* x1   = (u16*)(ws + 25165824);
    u16* mbuf = (u16*)(ws + 50331648);
    u16* offo = (u16*)(ws + 100663296);
    u16* cw   = (u16*)(ws + 103809024);
    int* flag = (int*)(ws + 118132416);

    u16* qkvw_c = cw +       0;
    u16* projw_c= cw + 1769472;
    u16* fc1w_c = cw + 2359296;
    u16* fc2w_c = cw + 4718592;
    u16* offw_c = cw + 7077888;
    u16* qkvb_c = cw + 7151616;
    u16* projb_c= cw + 7153920;
    u16* fc1b_c = cw + 7154688;
    u16* fc2b_c = cw + 7157760;
    u16* offb_c = cw + 7158528;
    u16* n1w_c  = cw + 7158624;
    u16* n1b_c  = cw + 7159392;
    u16* n2w_c  = cw + 7160160;
    u16* n2b_c  = cw + 7160928;

    dim3 blk(256);
    const int CH = 8192;                  // MLP row-chunk

    // 0) detect dtype, convert weights/biases to bf16
    flag_k<<<dim3(1), dim3(64), 0, stream>>>((const u16*)n1w, flag);
    convert_k<0, float><<<dim3(2048), blk, 0, stream>>>(flag, qkvw, projw, fc1w, fc2w, offw,
        qkvb, projb, fc1b, fc2b, offb, n1w, n1b, n2w, n2b, cw);
    convert_k<1, u16  ><<<dim3(2048), blk, 0, stream>>>(flag, qkvw, projw, fc1w, fc2w, offw,
        qkvb, projb, fc1b, fc2b, offb, n1w, n1b, n2w, n2b, cw);

    // 1) LN1: x -> h
    layernorm_k<0, float><<<dim3(M), blk, 0, stream>>>(flag, x, n1w_c, n1b_c, h);
    layernorm_k<1, u16  ><<<dim3(M), blk, 0, stream>>>(flag, x, n1w_c, n1b_c, h);
    // 2) qkv = h @ qkv_w^T + qkv_b
    gemm_nt<0, -1, u16, u16><<<dim3((3 * C_) / BN, M / BM), blk, 0, stream>>>(
        flag, h, C_, qkvw_c, qkvb_c, nullptr, qkv, M, 3 * C_, C_);
    // 3) off = q @ off_w^T + off_b   (q = first 768 cols of qkv, lda=2304)
    gemm_nt<0, -1, u16, u16><<<dim3(1, M / BM), blk, 0, stream>>>(
        flag, qkv, 3 * C_, offw_c, offb_c, nullptr, offo, M, HEADS_ * PTS_ * 2, C_);
    // 4) sampling + attention -> aout (h region dead)
    deform_attn<0, float><<<dim3(M * HEADS_ / 4), blk, 0, stream>>>(flag, qkv, offo, refp, aout);
    deform_attn<1, u16  ><<<dim3(M * HEADS_ / 4), blk, 0, stream>>>(flag, qkv, offo, refp, aout);
    // 5) x1 = x + aout @ proj_w^T + proj_b   (qkv region dead after this reads... qkv dead already)
    gemm_nt<2, 0, float, u16><<<dim3(C_ / BN, M / BM), blk, 0, stream>>>(
        flag, aout, C_, projw_c, projb_c, x, x1, M, C_, C_);
    gemm_nt<2, 1, u16,   u16><<<dim3(C_ / BN, M / BM), blk, 0, stream>>>(
        flag, aout, C_, projw_c, projb_c, x, x1, M, C_, C_);
    // 6) LN2: x1 -> h2 (aout dead)
    layernorm_k<-1, u16><<<dim3(M), blk, 0, stream>>>(flag, x1, n2w_c, n2b_c, h2);
    // 7/8) MLP in two 8192-row chunks
    for (int c = 0; c < 2; c++) {
        const u16* h2c = h2 + (size_t)c * CH * C_;
        const u16* x1c = x1 + (size_t)c * CH * C_;
        void* outc_f = (void*)((float*)d_out + (size_t)c * CH * C_);
        void* outc_b = (void*)((u16*)d_out + (size_t)c * CH * C_);
        gemm_nt<1, -1, u16, u16><<<dim3(HID_ / BN, CH / BM), blk, 0, stream>>>(
            flag, h2c, C_, fc1w_c, fc1b_c, nullptr, mbuf, CH, HID_, C_);
        gemm_nt<2, 0, u16, float><<<dim3(C_ / BN, CH / BM), blk, 0, stream>>>(
            flag, mbuf, HID_, fc2w_c, fc2b_c, x1c, outc_f, CH, C_, HID_);
        gemm_nt<2, 1, u16, u16  ><<<dim3(C_ / BN, CH / BM), blk, 0, stream>>>(
            flag, mbuf, HID_, fc2w_c, fc2b_c, x1c, outc_b, CH, C_, HID_);
    }
}

// Round 4
// 846.263 us; speedup vs baseline: 1.0372x; 1.0372x over previous
//
#include <hip/hip_runtime.h>
#include <cstdint>
#include <cstddef>

// Problem constants (from reference setup_inputs)
#define B_     4
#define N_     4096
#define C_     768
#define HEADS_ 12
#define PTS_   4
#define HD_    64
#define HID_   3072
#define HH_    64
#define WW_    64

typedef unsigned short u16;
typedef __bf16 bf16x8 __attribute__((ext_vector_type(8)));
typedef float  f32x4  __attribute__((ext_vector_type(4)));
typedef unsigned short ushort8 __attribute__((ext_vector_type(8)));

__device__ __forceinline__ float b2f(u16 x) {
    union { unsigned int u; float f; } v; v.u = ((unsigned int)x) << 16; return v.f;
}
__device__ __forceinline__ u16 f2bf(float f) {
    union { float f; unsigned int u; } v; v.f = f;
    unsigned int u = v.u;
    u = u + 0x7fffu + ((u >> 16) & 1u);   // RNE
    return (u16)(u >> 16);
}
// Force wave-uniformity: result lands in SGPRs, downstream int math -> SALU.
__device__ __forceinline__ int   ui(int x)   { return __builtin_amdgcn_readfirstlane(x); }
__device__ __forceinline__ float uf(float x) { return __int_as_float(__builtin_amdgcn_readfirstlane(__float_as_int(x))); }

// async global->LDS, 16B per lane. lds dst MUST be wave-uniform base;
// HW writes lane i at base + i*16 (guide §5, m97/m104).
__device__ __forceinline__ void gl16(const u16* g, u16* l) {
    __builtin_amdgcn_global_load_lds((const __attribute__((address_space(1))) void*)g,
                                     (__attribute__((address_space(3))) void*)l, 16, 0, 0);
}

// ---------------------------------------------------------------------------
// Runtime dtype detection: norm1_w is all-ones. fp32 1.0f -> u16[0]=0x0000;
// bf16 1.0 -> u16[0]=0x3F80. flag: 0 = fp32 inputs, 1 = bf16 inputs.
// ---------------------------------------------------------------------------
__global__ void flag_k(const u16* __restrict__ n1w, int* __restrict__ flag) {
    if (threadIdx.x == 0) flag[0] = (n1w[0] == 0x3F80u) ? 1 : 0;
}

// ---------------------------------------------------------------------------
// Convert all weights/biases to bf16 in workspace (copy if already bf16).
// ---------------------------------------------------------------------------
template <int WANT, typename T>
__global__ __launch_bounds__(256) void convert_k(
    const int* __restrict__ flag,
    const void* qkvw, const void* projw, const void* fc1w, const void* fc2w,
    const void* offw, const void* qkvb, const void* projb, const void* fc1b,
    const void* fc2b, const void* offb, const void* n1w, const void* n1b,
    const void* n2w, const void* n2b,
    u16* __restrict__ dst)
{
    if (*flag != WANT) return;
    const int total = 7161696;
    for (int i = (int)blockIdx.x * 256 + (int)threadIdx.x; i < total; i += (int)gridDim.x * 256) {
        const void* src; int off;
        if      (i < 1769472) { src = qkvw; off = i; }
        else if (i < 2359296) { src = projw; off = i - 1769472; }
        else if (i < 4718592) { src = fc1w;  off = i - 2359296; }
        else if (i < 7077888) { src = fc2w;  off = i - 4718592; }
        else if (i < 7151616) { src = offw;  off = i - 7077888; }
        else if (i < 7153920) { src = qkvb;  off = i - 7151616; }
        else if (i < 7154688) { src = projb; off = i - 7153920; }
        else if (i < 7157760) { src = fc1b;  off = i - 7154688; }
        else if (i < 7158528) { src = fc2b;  off = i - 7157760; }
        else if (i < 7158624) { src = offb;  off = i - 7158528; }
        else if (i < 7159392) { src = n1w;   off = i - 7158624; }
        else if (i < 7160160) { src = n1b;   off = i - 7159392; }
        else if (i < 7160928) { src = n2w;   off = i - 7160160; }
        else                  { src = n2b;   off = i - 7160928; }
        if constexpr (sizeof(T) == 4) dst[i] = f2bf(((const float*)src)[off]);
        else                          dst[i] = ((const u16*)src)[off];
    }
}

// ---------------------------------------------------------------------------
// GEMM: out[M,N] = epilogue(A[M,K(lda)] @ Bw[N,K]^T + bias[N])
// A/Bw/bias bf16. EPI: 0=bias; 1=bias+gelu; 2=bias+resid(TRES)->TOUT.
// 128x128x32 tile, 4 waves, 4x4 16x16x32 MFMA per wave.
// Staging: global_load_lds width=16 (m97 structure, 874 TF class).
// ---------------------------------------------------------------------------
#define BM 128
#define BN 128
#define BK 32

template <int EPI, int WANT, typename TRES, typename TOUT>
__global__ __launch_bounds__(256) void gemm_nt(
    const int* __restrict__ flag,
    const u16* __restrict__ A, int lda,
    const u16* __restrict__ Bw,
    const u16* __restrict__ bias,
    const void* __restrict__ resid,
    void* __restrict__ outv,
    int M, int N, int K)
{
    if constexpr (WANT >= 0) { if (*flag != WANT) return; }

    __shared__ alignas(16) u16 As[BM * BK];   // 8 KB, linear granule order
    __shared__ alignas(16) u16 Bs[BN * BK];   // 8 KB

    const int tid  = (int)threadIdx.x;
    const int wid  = tid >> 6;
    const int lane = tid & 63;
    const int l15  = lane & 15;
    const int quad = lane >> 4;
    const int m0   = (int)blockIdx.y * BM;
    const int n0   = (int)blockIdx.x * BN;
    const int wm   = (wid & 1) * 64;
    const int wn   = (wid >> 1) * 64;

    const f32x4 zero4 = {0.f, 0.f, 0.f, 0.f};
    f32x4 acc[4][4];
#pragma unroll
    for (int i = 0; i < 4; i++)
#pragma unroll
        for (int j = 0; j < 4; j++) acc[i][j] = zero4;

    // granule g holds tile elems [g*8, g*8+8) == row g>>2, cols (g&3)*8..+8
    const int g0 = tid, g1 = tid + 256;
    const int ar0 = g0 >> 2, ac0 = (g0 & 3) * 8;
    const int ar1 = g1 >> 2, ac1 = (g1 & 3) * 8;
    const u16* pa0 = A + (size_t)(m0 + ar0) * lda + ac0;
    const u16* pa1 = A + (size_t)(m0 + ar1) * lda + ac1;
    int br0 = n0 + ar0; if (br0 > N - 1) br0 = N - 1;
    int br1 = n0 + ar1; if (br1 > N - 1) br1 = N - 1;
    const u16* pb0 = Bw + (size_t)br0 * K + ac0;
    const u16* pb1 = Bw + (size_t)br1 * K + ac1;
    // wave-uniform LDS bases (lane writes base + lane*16B)
    u16* la0 = As + (size_t)(wid * 64) * 8;
    u16* la1 = As + (size_t)(wid * 64 + 256) * 8;
    u16* lb0 = Bs + (size_t)(wid * 64) * 8;
    u16* lb1 = Bs + (size_t)(wid * 64 + 256) * 8;

    for (int k0 = 0; k0 < K; k0 += BK) {
        __syncthreads();                 // prior tile fully consumed
        gl16(pa0 + k0, la0);
        gl16(pa1 + k0, la1);
        gl16(pb0 + k0, lb0);
        gl16(pb1 + k0, lb1);
        __syncthreads();                 // drains vmcnt, publishes LDS

        bf16x8 af[4], bfr[4];
#pragma unroll
        for (int i = 0; i < 4; i++)
            af[i] = *(const bf16x8*)(As + (wm + i * 16 + l15) * BK + quad * 8);
#pragma unroll
        for (int j = 0; j < 4; j++)
            bfr[j] = *(const bf16x8*)(Bs + (wn + j * 16 + l15) * BK + quad * 8);
#pragma unroll
        for (int i = 0; i < 4; i++)
#pragma unroll
            for (int j = 0; j < 4; j++)
                acc[i][j] = __builtin_amdgcn_mfma_f32_16x16x32_bf16(af[i], bfr[j], acc[i][j], 0, 0, 0);
    }

    // epilogue: reg r of acc[i][j] -> C[m0+wm+i*16+quad*4+r][n0+wn+j*16+l15]
#pragma unroll
    for (int j = 0; j < 4; j++) {
        int ncol = n0 + wn + j * 16 + l15;
        if (ncol >= N) continue;
        float bb = b2f(bias[ncol]);
#pragma unroll
        for (int i = 0; i < 4; i++) {
            int mbase = m0 + wm + i * 16 + quad * 4;
#pragma unroll
            for (int r = 0; r < 4; r++) {
                int m = mbase + r;
                float v = acc[i][j][r] + bb;
                size_t idx = (size_t)m * N + ncol;
                if (EPI == 0) {
                    ((u16*)outv)[idx] = f2bf(v);
                } else if (EPI == 1) {
                    float g = 0.5f * v * (1.0f + erff(v * 0.70710678118654752f));
                    ((u16*)outv)[idx] = f2bf(g);
                } else {
                    float res = (sizeof(TRES) == 4) ? ((const float*)resid)[idx]
                                                    : b2f(((const u16*)resid)[idx]);
                    float o = v + res;
                    if (sizeof(TOUT) == 4) ((float*)outv)[idx] = o;
                    else                   ((u16*)outv)[idx]   = f2bf(o);
                }
            }
        }
    }
}

// ---------------------------------------------------------------------------
// LayerNorm over last dim (768). One block (256 thr) per row. Output bf16.
// ---------------------------------------------------------------------------
template <int WANT, typename TIN>
__global__ __launch_bounds__(256) void layernorm_k(
    const int* __restrict__ flag,
    const void* __restrict__ xin,
    const u16* __restrict__ w,
    const u16* __restrict__ bb,
    u16* __restrict__ out)
{
    if constexpr (WANT >= 0) { if (*flag != WANT) return; }
    const int row = (int)blockIdx.x;
    const int tid = (int)threadIdx.x;
    float v[3];
    float s = 0.f, s2 = 0.f;
#pragma unroll
    for (int i = 0; i < 3; i++) {
        int c = tid + i * 256;
        float t = (sizeof(TIN) == 4) ? ((const float*)xin)[(size_t)row * C_ + c]
                                     : b2f(((const u16*)xin)[(size_t)row * C_ + c]);
        v[i] = t; s += t; s2 += t * t;
    }
#pragma unroll
    for (int o = 32; o > 0; o >>= 1) { s += __shfl_xor(s, o); s2 += __shfl_xor(s2, o); }
    __shared__ float red[8];
    const int wid = tid >> 6, lane = tid & 63;
    if (lane == 0) { red[wid] = s; red[4 + wid] = s2; }
    __syncthreads();
    s  = red[0] + red[1] + red[2] + red[3];
    s2 = red[4] + red[5] + red[6] + red[7];
    const float mean = s * (1.0f / C_);
    float var = s2 * (1.0f / C_) - mean * mean;
    const float rstd = rsqrtf(var + 1e-5f);
#pragma unroll
    for (int i = 0; i < 3; i++) {
        int c = tid + i * 256;
        float o_ = (v[i] - mean) * rstd * b2f(w[c]) + b2f(bb[c]);
        out[(size_t)row * C_ + c] = f2bf(o_);
    }
}

// ---------------------------------------------------------------------------
// Deformable sampling + attention. One wave per (b, head, n); lane = channel.
// All per-point math (coords, weights, validity, addresses) is wave-uniform:
// forced into SGPRs via readfirstlane so address arith + bounds go SALU.
// Per corner: 2 VMEM (SGPR base + lane offset) + 2 shifts + 2 FMA.
// ---------------------------------------------------------------------------
template <typename TR>
__device__ __forceinline__ void deform_body(
    const u16* __restrict__ qkv,
    const u16* __restrict__ off,
    const void* __restrict__ refp,
    u16* __restrict__ out)
{
    const int tid  = (int)threadIdx.x;
    const int wid  = tid >> 6;
    const int lane = tid & 63;
    const int wav  = (int)blockIdx.x * 4 + wid;      // 0 .. B*N*HEADS-1
    const int h    = ui(wav % HEADS_);
    const int bn   = ui(wav / HEADS_);               // b*N + n
    const int b    = bn >> 12;

    const float qd = b2f(qkv[(size_t)bn * (3 * C_) + h * HD_ + lane]);
    float rx, ry;
    if constexpr (sizeof(TR) == 4) {
        rx = uf(((const float*)refp)[(size_t)bn * 2 + 0]);
        ry = uf(((const float*)refp)[(size_t)bn * 2 + 1]);
    } else {
        rx = uf(b2f(((const u16*)refp)[(size_t)bn * 2 + 0]));
        ry = uf(b2f(((const u16*)refp)[(size_t)bn * 2 + 1]));
    }
    // uniform base (element index) of the k plane for this (b,h): + lane later
    const size_t kbase0 = (size_t)b * N_ * (3 * C_) + C_ + h * HD_;
    const size_t obase  = (size_t)bn * (HEADS_ * PTS_ * 2) + h * (PTS_ * 2);

    float logit[PTS_], svd[PTS_];
#pragma unroll
    for (int p = 0; p < PTS_; p++) {
        const float ox = uf(b2f(off[obase + p * 2 + 0]));
        const float oy = uf(b2f(off[obase + p * 2 + 1]));
        float px = rx * (float)WW_ + ox - 0.5f;
        float py = ry * (float)HH_ + oy - 0.5f;
        px = fminf(fmaxf(px, -8.f), 72.f);   // NaN/garbage-proof
        py = fminf(fmaxf(py, -8.f), 72.f);
        const float x0f = floorf(px), y0f = floorf(py);
        const int x0 = ui((int)x0f), y0 = ui((int)y0f);
        const float wx = uf(px - x0f), wy = uf(py - y0f);
        const float w00 = (1.f - wx) * (1.f - wy);
        const float w01 = wx * (1.f - wy);
        const float w10 = (1.f - wx) * wy;
        const float w11 = wx * wy;
        float sk = 0.f, sv = 0.f;
#pragma unroll
        for (int c = 0; c < 4; c++) {
            const int xi = x0 + (c & 1);
            const int yi = y0 + (c >> 1);
            if (xi >= 0 && xi < WW_ && yi >= 0 && yi < HH_) {   // uniform branch
                const float wgt = (c == 0) ? w00 : (c == 1) ? w01 : (c == 2) ? w10 : w11;
                const u16* kp = qkv + kbase0 + (size_t)(yi * WW_ + xi) * (3 * C_);
                sk = fmaf(wgt, b2f(kp[lane]), sk);
                sv = fmaf(wgt, b2f(kp[lane + C_]), sv);
            }
        }
        logit[p] = qd * sk;
        svd[p]   = sv;
    }
#pragma unroll
    for (int p = 0; p < PTS_; p++)
#pragma unroll
        for (int o = 32; o > 0; o >>= 1) logit[p] += __shfl_xor(logit[p], o);

    const float scale = 0.125f;  // HD^-0.5
    float l0 = logit[0] * scale, l1 = logit[1] * scale, l2 = logit[2] * scale, l3 = logit[3] * scale;
    float mx = fmaxf(fmaxf(l0, l1), fmaxf(l2, l3));
    float e0 = __expf(l0 - mx), e1 = __expf(l1 - mx), e2 = __expf(l2 - mx), e3 = __expf(l3 - mx);
    float Z = e0 + e1 + e2 + e3;
    float od = (e0 * svd[0] + e1 * svd[1] + e2 * svd[2] + e3 * svd[3]) / Z;
    out[(size_t)bn * C_ + h * HD_ + lane] = f2bf(od);
}

// distinct names so rocprof reveals which dtype mode actually runs
__global__ __launch_bounds__(256) void deform_attn_f32(
    const int* __restrict__ flag, const u16* __restrict__ qkv,
    const u16* __restrict__ off, const void* __restrict__ refp, u16* __restrict__ out)
{
    if (*flag != 0) return;
    deform_body<float>(qkv, off, refp, out);
}
__global__ __launch_bounds__(256) void deform_attn_bf16(
    const int* __restrict__ flag, const u16* __restrict__ qkv,
    const u16* __restrict__ off, const void* __restrict__ refp, u16* __restrict__ out)
{
    if (*flag != 1) return;
    deform_body<u16>(qkv, off, refp, out);
}

// ---------------------------------------------------------------------------
extern "C" void kernel_launch(void* const* d_in, const int* in_sizes, int n_in,
                              void* d_out, int out_size, void* d_ws, size_t ws_size,
                              hipStream_t stream)
{
    const void* x     = d_in[0];
    const void* refp  = d_in[1];
    const void* n1w   = d_in[2];
    const void* n1b   = d_in[3];
    const void* qkvw  = d_in[4];
    const void* qkvb  = d_in[5];
    const void* offw  = d_in[6];
    const void* offb  = d_in[7];
    const void* projw = d_in[8];
    const void* projb = d_in[9];
    const void* n2w   = d_in[10];
    const void* n2b   = d_in[11];
    const void* fc1w  = d_in[12];
    const void* fc1b  = d_in[13];
    const void* fc2w  = d_in[14];
    const void* fc2b  = d_in[15];
    (void)in_sizes; (void)n_in; (void)out_size; (void)ws_size;

    const int M = B_ * N_;  // 16384

    // Workspace layout — peak 118,132,420 B:
    //   A [0,         25165824): h (s1-2) -> aout (s4-5) -> h2 (s6-7)
    //   B [25165824, 100663296): qkv (s2-4) -> x1 [25.1M,50.3M) + mbuf [50.3M,100.66M)
    //   C [100663296,103809024): offo (s3-4)
    //   D [103809024,118132416): converted weights/biases (bf16)
    //   E [118132416,118132420): dtype flag (int)
    char* ws = (char*)d_ws;
    u16* h    = (u16*)(ws);
    u16* aout = (u16*)(ws);
    u16* h2   = (u16*)(ws);
    u16* qkv  = (u16*)(ws + 25165824);
    u16* x1   = (u16*)(ws + 25165824);
    u16* mbuf = (u16*)(ws + 50331648);
    u16* offo = (u16*)(ws + 100663296);
    u16* cw   = (u16*)(ws + 103809024);
    int* flag = (int*)(ws + 118132416);

    u16* qkvw_c = cw +       0;
    u16* projw_c= cw + 1769472;
    u16* fc1w_c = cw + 2359296;
    u16* fc2w_c = cw + 4718592;
    u16* offw_c = cw + 7077888;
    u16* qkvb_c = cw + 7151616;
    u16* projb_c= cw + 7153920;
    u16* fc1b_c = cw + 7154688;
    u16* fc2b_c = cw + 7157760;
    u16* offb_c = cw + 7158528;
    u16* n1w_c  = cw + 7158624;
    u16* n1b_c  = cw + 7159392;
    u16* n2w_c  = cw + 7160160;
    u16* n2b_c  = cw + 7160928;

    dim3 blk(256);
    const int CH = 8192;                  // MLP row-chunk

    // 0) detect dtype, convert weights/biases to bf16
    flag_k<<<dim3(1), dim3(64), 0, stream>>>((const u16*)n1w, flag);
    convert_k<0, float><<<dim3(2048), blk, 0, stream>>>(flag, qkvw, projw, fc1w, fc2w, offw,
        qkvb, projb, fc1b, fc2b, offb, n1w, n1b, n2w, n2b, cw);
    convert_k<1, u16  ><<<dim3(2048), blk, 0, stream>>>(flag, qkvw, projw, fc1w, fc2w, offw,
        qkvb, projb, fc1b, fc2b, offb, n1w, n1b, n2w, n2b, cw);

    // 1) LN1: x -> h
    layernorm_k<0, float><<<dim3(M), blk, 0, stream>>>(flag, x, n1w_c, n1b_c, h);
    layernorm_k<1, u16  ><<<dim3(M), blk, 0, stream>>>(flag, x, n1w_c, n1b_c, h);
    // 2) qkv = h @ qkv_w^T + qkv_b
    gemm_nt<0, -1, u16, u16><<<dim3((3 * C_) / BN, M / BM), blk, 0, stream>>>(
        flag, h, C_, qkvw_c, qkvb_c, nullptr, qkv, M, 3 * C_, C_);
    // 3) off = q @ off_w^T + off_b   (q = first 768 cols of qkv, lda=2304)
    gemm_nt<0, -1, u16, u16><<<dim3(1, M / BM), blk, 0, stream>>>(
        flag, qkv, 3 * C_, offw_c, offb_c, nullptr, offo, M, HEADS_ * PTS_ * 2, C_);
    // 4) sampling + attention -> aout (h region dead)
    deform_attn_f32 <<<dim3(M * HEADS_ / 4), blk, 0, stream>>>(flag, qkv, offo, refp, aout);
    deform_attn_bf16<<<dim3(M * HEADS_ / 4), blk, 0, stream>>>(flag, qkv, offo, refp, aout);
    // 5) x1 = x + aout @ proj_w^T + proj_b   (qkv region dead)
    gemm_nt<2, 0, float, u16><<<dim3(C_ / BN, M / BM), blk, 0, stream>>>(
        flag, aout, C_, projw_c, projb_c, x, x1, M, C_, C_);
    gemm_nt<2, 1, u16,   u16><<<dim3(C_ / BN, M / BM), blk, 0, stream>>>(
        flag, aout, C_, projw_c, projb_c, x, x1, M, C_, C_);
    // 6) LN2: x1 -> h2 (aout dead)
    layernorm_k<-1, u16><<<dim3(M), blk, 0, stream>>>(flag, x1, n2w_c, n2b_c, h2);
    // 7/8) MLP in two 8192-row chunks
    for (int c = 0; c < 2; c++) {
        const u16* h2c = h2 + (size_t)c * CH * C_;
        const u16* x1c = x1 + (size_t)c * CH * C_;
        void* outc_f = (void*)((float*)d_out + (size_t)c * CH * C_);
        void* outc_b = (void*)((u16*)d_out + (size_t)c * CH * C_);
        gemm_nt<1, -1, u16, u16><<<dim3(HID_ / BN, CH / BM), blk, 0, stream>>>(
            flag, h2c, C_, fc1w_c, fc1b_c, nullptr, mbuf, CH, HID_, C_);
        gemm_nt<2, 0, u16, float><<<dim3(C_ / BN, CH / BM), blk, 0, stream>>>(
            flag, mbuf, HID_, fc2w_c, fc2b_c, x1c, outc_f, CH, C_, HID_);
        gemm_nt<2, 1, u16, u16  ><<<dim3(C_ / BN, CH / BM), blk, 0, stream>>>(
            flag, mbuf, HID_, fc2w_c, fc2b_c, x1c, outc_b, CH, C_, HID_);
    }
}

// Round 5
// 838.539 us; speedup vs baseline: 1.0468x; 1.0092x over previous
//
#include <hip/hip_runtime.h>
#include <cstdint>
#include <cstddef>

// Problem constants (from reference setup_inputs). Inputs/outputs are fp32
// (confirmed R4: deform_attn_f32 was the live dispatch; fp32 output passed).
#define B_     4
#define N_     4096
#define C_     768
#define HEADS_ 12
#define PTS_   4
#define HD_    64
#define HID_   3072
#define HH_    64
#define WW_    64

typedef unsigned short u16;
typedef unsigned int   u32;
typedef __bf16 bf16x8 __attribute__((ext_vector_type(8)));
typedef float  f32x4  __attribute__((ext_vector_type(4)));
typedef unsigned short ushort8 __attribute__((ext_vector_type(8)));

__device__ __forceinline__ float b2f(u16 x) {
    union { unsigned int u; float f; } v; v.u = ((unsigned int)x) << 16; return v.f;
}
__device__ __forceinline__ u16 f2bf(float f) {
    union { float f; unsigned int u; } v; v.f = f;
    unsigned int u = v.u;
    u = u + 0x7fffu + ((u >> 16) & 1u);   // RNE
    return (u16)(u >> 16);
}
// Force wave-uniformity: result lands in SGPRs, downstream math -> SALU.
__device__ __forceinline__ int   ui(int x)   { return __builtin_amdgcn_readfirstlane(x); }
__device__ __forceinline__ float uf(float x) { return __int_as_float(__builtin_amdgcn_readfirstlane(__float_as_int(x))); }

// async global->LDS, 16B per lane. LDS dst is wave-uniform base; HW writes
// lane i at base + i*16 (guide §5, m97/m104).
__device__ __forceinline__ void gl16(const u16* g, u16* l) {
    __builtin_amdgcn_global_load_lds((const __attribute__((address_space(1))) void*)g,
                                     (__attribute__((address_space(3))) void*)l, 16, 0, 0);
}

// ---------------------------------------------------------------------------
// Convert all fp32 weights/biases to bf16 in workspace.
// Segment element offsets: qkvw 0, projw 1769472, fc1w 2359296, fc2w 4718592,
// offw 7077888, qkvb 7151616, projb 7153920, fc1b 7154688, fc2b 7157760,
// offb 7158528, n1w 7158624, n1b 7159392, n2w 7160160, n2b 7160928; total 7161696.
// ---------------------------------------------------------------------------
__global__ __launch_bounds__(256) void convert_k(
    const float* qkvw, const float* projw, const float* fc1w, const float* fc2w,
    const float* offw, const float* qkvb, const float* projb, const float* fc1b,
    const float* fc2b, const float* offb, const float* n1w, const float* n1b,
    const float* n2w, const float* n2b,
    u16* __restrict__ dst)
{
    const int total = 7161696;
    for (int i = (int)blockIdx.x * 256 + (int)threadIdx.x; i < total; i += (int)gridDim.x * 256) {
        const float* src; int off;
        if      (i < 1769472) { src = qkvw;  off = i; }
        else if (i < 2359296) { src = projw; off = i - 1769472; }
        else if (i < 4718592) { src = fc1w;  off = i - 2359296; }
        else if (i < 7077888) { src = fc2w;  off = i - 4718592; }
        else if (i < 7151616) { src = offw;  off = i - 7077888; }
        else if (i < 7153920) { src = qkvb;  off = i - 7151616; }
        else if (i < 7154688) { src = projb; off = i - 7153920; }
        else if (i < 7157760) { src = fc1b;  off = i - 7154688; }
        else if (i < 7158528) { src = fc2b;  off = i - 7157760; }
        else if (i < 7158624) { src = offb;  off = i - 7158528; }
        else if (i < 7159392) { src = n1w;   off = i - 7158624; }
        else if (i < 7160160) { src = n1b;   off = i - 7159392; }
        else if (i < 7160928) { src = n2w;   off = i - 7160160; }
        else                  { src = n2b;   off = i - 7160928; }
        dst[i] = f2bf(src[off]);
    }
}

// ---------------------------------------------------------------------------
// GEMM: out[M,N] = epilogue(A[M,K(lda)] @ Bw[N,K]^T + bias[N])
// A/Bw/bias bf16. EPI: 0=bias->bf16; 1=bias+gelu->bf16; 2=bias+resid(TRES)->TOUT.
// 128x128x64 tile, 4 waves, 4x4 of 16x16x32 MFMA x2 K-halves per iter.
// BK=64: 32 MFMA per barrier pair (vs 16 at BK=32) — halves barrier drains.
// Staging: global_load_lds width=16, linear granule order.
// ---------------------------------------------------------------------------
#define BM 128
#define BN 128
#define BK 64

template <int EPI, typename TRES, typename TOUT>
__global__ __launch_bounds__(256) void gemm_nt(
    const u16* __restrict__ A, int lda,
    const u16* __restrict__ Bw,
    const u16* __restrict__ bias,
    const void* __restrict__ resid,
    void* __restrict__ outv,
    int M, int N, int K)
{
    __shared__ alignas(16) u16 As[BM * BK];   // 16 KB
    __shared__ alignas(16) u16 Bs[BN * BK];   // 16 KB

    const int tid  = (int)threadIdx.x;
    const int wid  = tid >> 6;
    const int lane = tid & 63;
    const int l15  = lane & 15;
    const int quad = lane >> 4;
    const int m0   = (int)blockIdx.y * BM;
    const int n0   = (int)blockIdx.x * BN;
    const int wm   = (wid & 1) * 64;
    const int wn   = (wid >> 1) * 64;

    const f32x4 zero4 = {0.f, 0.f, 0.f, 0.f};
    f32x4 acc[4][4];
#pragma unroll
    for (int i = 0; i < 4; i++)
#pragma unroll
        for (int j = 0; j < 4; j++) acc[i][j] = zero4;

    // granule g (16B) = tile row g>>3, cols (g&7)*8..+8; thread handles
    // g = tid + q*256, q=0..3. Wave-uniform LDS base per q-group.
    const int srow = tid >> 3;          // 0..31
    const int scol = (tid & 7) * 8;     // 0,8,..,56
    const u16* pa = A + (size_t)(m0 + srow) * lda + scol;
    int brow[4];
#pragma unroll
    for (int q = 0; q < 4; q++) {
        int r = n0 + srow + q * 32;
        brow[q] = (r > N - 1) ? (N - 1) : r;
    }

    for (int k0 = 0; k0 < K; k0 += BK) {
        __syncthreads();                 // prior tile fully consumed
#pragma unroll
        for (int q = 0; q < 4; q++) {
            gl16(pa + (size_t)(q * 32) * lda + k0, As + (size_t)(q * 256 + wid * 64) * 8);
            gl16(Bw + (size_t)brow[q] * K + scol + k0, Bs + (size_t)(q * 256 + wid * 64) * 8);
        }
        __syncthreads();                 // drains vmcnt, publishes LDS

#pragma unroll
        for (int half = 0; half < 2; half++) {
            bf16x8 af[4], bfr[4];
#pragma unroll
            for (int i = 0; i < 4; i++)
                af[i] = *(const bf16x8*)(As + (wm + i * 16 + l15) * BK + half * 32 + quad * 8);
#pragma unroll
            for (int j = 0; j < 4; j++)
                bfr[j] = *(const bf16x8*)(Bs + (wn + j * 16 + l15) * BK + half * 32 + quad * 8);
#pragma unroll
            for (int i = 0; i < 4; i++)
#pragma unroll
                for (int j = 0; j < 4; j++)
                    acc[i][j] = __builtin_amdgcn_mfma_f32_16x16x32_bf16(af[i], bfr[j], acc[i][j], 0, 0, 0);
        }
    }

    // epilogue: reg r of acc[i][j] -> C[m0+wm+i*16+quad*4+r][n0+wn+j*16+l15]
#pragma unroll
    for (int j = 0; j < 4; j++) {
        int ncol = n0 + wn + j * 16 + l15;
        if (ncol >= N) continue;
        float bb = b2f(bias[ncol]);
#pragma unroll
        for (int i = 0; i < 4; i++) {
            int mbase = m0 + wm + i * 16 + quad * 4;
#pragma unroll
            for (int r = 0; r < 4; r++) {
                int m = mbase + r;
                float v = acc[i][j][r] + bb;
                size_t idx = (size_t)m * N + ncol;
                if (EPI == 0) {
                    ((u16*)outv)[idx] = f2bf(v);
                } else if (EPI == 1) {
                    float g = 0.5f * v * (1.0f + erff(v * 0.70710678118654752f));
                    ((u16*)outv)[idx] = f2bf(g);
                } else {
                    float res = (sizeof(TRES) == 4) ? ((const float*)resid)[idx]
                                                    : b2f(((const u16*)resid)[idx]);
                    float o = v + res;
                    if (sizeof(TOUT) == 4) ((float*)outv)[idx] = o;
                    else                   ((u16*)outv)[idx]   = f2bf(o);
                }
            }
        }
    }
}

// ---------------------------------------------------------------------------
// LayerNorm over last dim (768). One block (256 thr) per row. Output bf16.
// TIN = float (x) or u16 (ws bf16).
// ---------------------------------------------------------------------------
template <typename TIN>
__global__ __launch_bounds__(256) void layernorm_k(
    const void* __restrict__ xin,
    const u16* __restrict__ w,
    const u16* __restrict__ bb,
    u16* __restrict__ out)
{
    const int row = (int)blockIdx.x;
    const int tid = (int)threadIdx.x;
    float v[3];
    float s = 0.f, s2 = 0.f;
#pragma unroll
    for (int i = 0; i < 3; i++) {
        int c = tid + i * 256;
        float t = (sizeof(TIN) == 4) ? ((const float*)xin)[(size_t)row * C_ + c]
                                     : b2f(((const u16*)xin)[(size_t)row * C_ + c]);
        v[i] = t; s += t; s2 += t * t;
    }
#pragma unroll
    for (int o = 32; o > 0; o >>= 1) { s += __shfl_xor(s, o); s2 += __shfl_xor(s2, o); }
    __shared__ float red[8];
    const int wid = tid >> 6, lane = tid & 63;
    if (lane == 0) { red[wid] = s; red[4 + wid] = s2; }
    __syncthreads();
    s  = red[0] + red[1] + red[2] + red[3];
    s2 = red[4] + red[5] + red[6] + red[7];
    const float mean = s * (1.0f / C_);
    float var = s2 * (1.0f / C_) - mean * mean;
    const float rstd = rsqrtf(var + 1e-5f);
#pragma unroll
    for (int i = 0; i < 3; i++) {
        int c = tid + i * 256;
        float o_ = (v[i] - mean) * rstd * b2f(w[c]) + b2f(bb[c]);
        out[(size_t)row * C_ + c] = f2bf(o_);
    }
}

// ---------------------------------------------------------------------------
// In-place kv interleave: row bn of qkv [2304 u16] has q|k|v. Rewrites cols
// [768,2304) so channel d's (k,v) form one u32: row32[384+c] = k[c] | v[c]<<16.
// One block per row; all reads complete before writes (block barrier).
// ---------------------------------------------------------------------------
__global__ __launch_bounds__(256) void kv_interleave(u16* __restrict__ qkv)
{
    const int row = (int)blockIdx.x;
    const int tid = (int)threadIdx.x;
    u16* rp = qkv + (size_t)row * 2304;
    u16 kk[3], vv[3];
#pragma unroll
    for (int i = 0; i < 3; i++) {
        int c = tid + i * 256;
        kk[i] = rp[768 + c];
        vv[i] = rp[1536 + c];
    }
    __syncthreads();
    u32* rp32 = (u32*)rp;
#pragma unroll
    for (int i = 0; i < 3; i++) {
        int c = tid + i * 256;
        rp32[384 + c] = (u32)kk[i] | ((u32)vv[i] << 16);
    }
}

// ---------------------------------------------------------------------------
// Deformable sampling + attention. One wave per (b, head, n); lane = channel.
// All per-point math wave-uniform (SALU); per corner ONE global_load_dword
// of the interleaved (k,v) pair; bf16 unpack is free shift/mask.
// ---------------------------------------------------------------------------
__global__ __launch_bounds__(256) void deform_attn(
    const u16* __restrict__ qkv,
    const u16* __restrict__ off,
    const float* __restrict__ refp,
    u16* __restrict__ out)
{
    const int tid  = (int)threadIdx.x;
    const int wid  = tid >> 6;
    const int lane = tid & 63;
    const int wav  = (int)blockIdx.x * 4 + wid;      // 0 .. B*N*HEADS-1
    const int h    = ui(wav % HEADS_);
    const int bn   = ui(wav / HEADS_);               // b*N + n
    const int b    = bn >> 12;

    const float qd = b2f(qkv[(size_t)bn * (3 * C_) + h * HD_ + lane]);
    const float rx = uf(refp[(size_t)bn * 2 + 0]);
    const float ry = uf(refp[(size_t)bn * 2 + 1]);

    // one 16B broadcast load for all 8 offsets of this (bn,h)
    const ushort8 ov = *(const ushort8*)(off + (size_t)bn * (HEADS_ * PTS_ * 2) + h * (PTS_ * 2));

    const u32* q32 = (const u32*)qkv;
    const int ibase = (b << 12);                     // image row base (b*N)
    const int cbase = 384 + h * HD_ + lane;          // u32 index within row

    float logit[PTS_], svd[PTS_];
#pragma unroll
    for (int p = 0; p < PTS_; p++) {
        const float ox = uf(b2f(ov[p * 2 + 0]));
        const float oy = uf(b2f(ov[p * 2 + 1]));
        float px = rx * (float)WW_ + ox - 0.5f;
        float py = ry * (float)HH_ + oy - 0.5f;
        px = fminf(fmaxf(px, -8.f), 72.f);           // NaN/garbage-proof
        py = fminf(fmaxf(py, -8.f), 72.f);
        const float x0f = floorf(px), y0f = floorf(py);
        const int x0 = ui((int)x0f), y0 = ui((int)y0f);
        const float wx = uf(px - x0f), wy = uf(py - y0f);
        const float w00 = (1.f - wx) * (1.f - wy);
        const float w01 = wx * (1.f - wy);
        const float w10 = (1.f - wx) * wy;
        const float w11 = wx * wy;
        float sk = 0.f, sv = 0.f;
#pragma unroll
        for (int c = 0; c < 4; c++) {
            const int xi = x0 + (c & 1);
            const int yi = y0 + (c >> 1);
            if (xi >= 0 && xi < WW_ && yi >= 0 && yi < HH_) {   // uniform branch
                const float wgt = (c == 0) ? w00 : (c == 1) ? w01 : (c == 2) ? w10 : w11;
                const u32 kv = q32[(size_t)(ibase + yi * WW_ + xi) * 1152 + cbase];
                sk = fmaf(wgt, __int_as_float((int)(kv << 16)), sk);
                sv = fmaf(wgt, __int_as_float((int)(kv & 0xffff0000u)), sv);
            }
        }
        logit[p] = qd * sk;
        svd[p]   = sv;
    }
#pragma unroll
    for (int p = 0; p < PTS_; p++)
#pragma unroll
        for (int o = 32; o > 0; o >>= 1) logit[p] += __shfl_xor(logit[p], o);

    const float scale = 0.125f;  // HD^-0.5
    float l0 = logit[0] * scale, l1 = logit[1] * scale, l2 = logit[2] * scale, l3 = logit[3] * scale;
    float mx = fmaxf(fmaxf(l0, l1), fmaxf(l2, l3));
    float e0 = __expf(l0 - mx), e1 = __expf(l1 - mx), e2 = __expf(l2 - mx), e3 = __expf(l3 - mx);
    float Z = e0 + e1 + e2 + e3;
    float od = (e0 * svd[0] + e1 * svd[1] + e2 * svd[2] + e3 * svd[3]) / Z;
    out[(size_t)bn * C_ + h * HD_ + lane] = f2bf(od);
}

// ---------------------------------------------------------------------------
extern "C" void kernel_launch(void* const* d_in, const int* in_sizes, int n_in,
                              void* d_out, int out_size, void* d_ws, size_t ws_size,
                              hipStream_t stream)
{
    const float* x     = (const float*)d_in[0];
    const float* refp  = (const float*)d_in[1];
    const float* n1w   = (const float*)d_in[2];
    const float* n1b   = (const float*)d_in[3];
    const float* qkvw  = (const float*)d_in[4];
    const float* qkvb  = (const float*)d_in[5];
    const float* offw  = (const float*)d_in[6];
    const float* offb  = (const float*)d_in[7];
    const float* projw = (const float*)d_in[8];
    const float* projb = (const float*)d_in[9];
    const float* n2w   = (const float*)d_in[10];
    const float* n2b   = (const float*)d_in[11];
    const float* fc1w  = (const float*)d_in[12];
    const float* fc1b  = (const float*)d_in[13];
    const float* fc2w  = (const float*)d_in[14];
    const float* fc2b  = (const float*)d_in[15];
    (void)in_sizes; (void)n_in; (void)out_size; (void)ws_size;

    const int M = B_ * N_;  // 16384

    // Workspace layout — peak 118,132,416 B:
    //   A [0,         25165824): h (LN1 out) -> aout -> h2 (LN2 out)
    //   B [25165824, 100663296): qkv (kv interleaved in place)
    //                            -> x1 [25.1M,50.3M) + mbuf [50.3M,100.66M)
    //   C [100663296,103809024): offo
    //   D [103809024,118132416): converted bf16 weights/biases
    char* ws = (char*)d_ws;
    u16* h    = (u16*)(ws);
    u16* aout = (u16*)(ws);
    u16* h2   = (u16*)(ws);
    u16* qkv  = (u16*)(ws + 25165824);
    u16* x1   = (u16*)(ws + 25165824);
    u16* mbuf = (u16*)(ws + 50331648);
    u16* offo = (u16*)(ws + 100663296);
    u16* cw   = (u16*)(ws + 103809024);

    u16* qkvw_c = cw +       0;
    u16* projw_c= cw + 1769472;
    u16* fc1w_c = cw + 2359296;
    u16* fc2w_c = cw + 4718592;
    u16* offw_c = cw + 7077888;
    u16* qkvb_c = cw + 7151616;
    u16* projb_c= cw + 7153920;
    u16* fc1b_c = cw + 7154688;
    u16* fc2b_c = cw + 7157760;
    u16* offb_c = cw + 7158528;
    u16* n1w_c  = cw + 7158624;
    u16* n1b_c  = cw + 7159392;
    u16* n2w_c  = cw + 7160160;
    u16* n2b_c  = cw + 7160928;

    dim3 blk(256);
    const int CH = 8192;                  // MLP row-chunk

    // 0) convert fp32 weights/biases to bf16
    convert_k<<<dim3(2048), blk, 0, stream>>>(qkvw, projw, fc1w, fc2w, offw,
        qkvb, projb, fc1b, fc2b, offb, n1w, n1b, n2w, n2b, cw);
    // 1) LN1: x -> h
    layernorm_k<float><<<dim3(M), blk, 0, stream>>>(x, n1w_c, n1b_c, h);
    // 2) qkv = h @ qkv_w^T + qkv_b
    gemm_nt<0, u16, u16><<<dim3((3 * C_) / BN, M / BM), blk, 0, stream>>>(
        h, C_, qkvw_c, qkvb_c, nullptr, qkv, M, 3 * C_, C_);
    // 3) off = q @ off_w^T + off_b   (q = first 768 cols of qkv, lda=2304)
    gemm_nt<0, u16, u16><<<dim3(1, M / BM), blk, 0, stream>>>(
        qkv, 3 * C_, offw_c, offb_c, nullptr, offo, M, HEADS_ * PTS_ * 2, C_);
    // 4a) interleave k,v in place (q untouched)
    kv_interleave<<<dim3(M), blk, 0, stream>>>(qkv);
    // 4b) sampling + attention -> aout (h region dead)
    deform_attn<<<dim3(M * HEADS_ / 4), blk, 0, stream>>>(qkv, offo, refp, aout);
    // 5) x1 = x + aout @ proj_w^T + proj_b   (qkv region dead -> x1)
    gemm_nt<2, float, u16><<<dim3(C_ / BN, M / BM), blk, 0, stream>>>(
        aout, C_, projw_c, projb_c, x, x1, M, C_, C_);
    // 6) LN2: x1 -> h2 (aout dead)
    layernorm_k<u16><<<dim3(M), blk, 0, stream>>>(x1, n2w_c, n2b_c, h2);
    // 7/8) MLP in two 8192-row chunks (bounds mbuf at 50 MB)
    for (int c = 0; c < 2; c++) {
        const u16* h2c = h2 + (size_t)c * CH * C_;
        const u16* x1c = x1 + (size_t)c * CH * C_;
        float* outc = (float*)d_out + (size_t)c * CH * C_;
        gemm_nt<1, u16, u16><<<dim3(HID_ / BN, CH / BM), blk, 0, stream>>>(
            h2c, C_, fc1w_c, fc1b_c, nullptr, mbuf, CH, HID_, C_);
        gemm_nt<2, u16, float><<<dim3(C_ / BN, CH / BM), blk, 0, stream>>>(
            mbuf, HID_, fc2w_c, fc2b_c, x1c, outc, CH, C_, HID_);
    }
}

// Round 6
// 742.917 us; speedup vs baseline: 1.1815x; 1.1287x over previous
//
#include <hip/hip_runtime.h>
#include <cstdint>
#include <cstddef>

// Problem constants. Inputs/outputs fp32 (confirmed R4).
#define B_     4
#define N_     4096
#define C_     768
#define HEADS_ 12
#define PTS_   4
#define HD_    64
#define HID_   3072
#define HH_    64
#define WW_    64

typedef unsigned short u16;
typedef unsigned int   u32;
typedef __bf16 bf16x8 __attribute__((ext_vector_type(8)));
typedef float  f32x4  __attribute__((ext_vector_type(4)));
typedef unsigned short ushort8 __attribute__((ext_vector_type(8)));

__device__ __forceinline__ float b2f(u16 x) {
    union { unsigned int u; float f; } v; v.u = ((unsigned int)x) << 16; return v.f;
}
__device__ __forceinline__ u16 f2bf(float f) {
    union { float f; unsigned int u; } v; v.f = f;
    unsigned int u = v.u;
    u = u + 0x7fffu + ((u >> 16) & 1u);   // RNE
    return (u16)(u >> 16);
}
__device__ __forceinline__ int   ui(int x)   { return __builtin_amdgcn_readfirstlane(x); }
__device__ __forceinline__ float uf(float x) { return __int_as_float(__builtin_amdgcn_readfirstlane(__float_as_int(x))); }

// async global->LDS, 16B/lane; LDS dst wave-uniform base, lane i -> base+i*16.
__device__ __forceinline__ void gl16(const u16* g, u16* l) {
    __builtin_amdgcn_global_load_lds((const __attribute__((address_space(1))) void*)g,
                                     (__attribute__((address_space(3))) void*)l, 16, 0, 0);
}

// ---------------------------------------------------------------------------
// fp32 weights/biases -> bf16 workspace (segment offsets in comments R5).
// ---------------------------------------------------------------------------
__global__ __launch_bounds__(256) void convert_k(
    const float* qkvw, const float* projw, const float* fc1w, const float* fc2w,
    const float* offw, const float* qkvb, const float* projb, const float* fc1b,
    const float* fc2b, const float* offb, const float* n1w, const float* n1b,
    const float* n2w, const float* n2b,
    u16* __restrict__ dst)
{
    const int total = 7161696;
    for (int i = (int)blockIdx.x * 256 + (int)threadIdx.x; i < total; i += (int)gridDim.x * 256) {
        const float* src; int off;
        if      (i < 1769472) { src = qkvw;  off = i; }
        else if (i < 2359296) { src = projw; off = i - 1769472; }
        else if (i < 4718592) { src = fc1w;  off = i - 2359296; }
        else if (i < 7077888) { src = fc2w;  off = i - 4718592; }
        else if (i < 7151616) { src = offw;  off = i - 7077888; }
        else if (i < 7153920) { src = qkvb;  off = i - 7151616; }
        else if (i < 7154688) { src = projb; off = i - 7153920; }
        else if (i < 7157760) { src = fc1b;  off = i - 7154688; }
        else if (i < 7158528) { src = fc2b;  off = i - 7157760; }
        else if (i < 7158624) { src = offb;  off = i - 7158528; }
        else if (i < 7159392) { src = n1w;   off = i - 7158624; }
        else if (i < 7160160) { src = n1b;   off = i - 7159392; }
        else if (i < 7160928) { src = n2w;   off = i - 7160160; }
        else                  { src = n2b;   off = i - 7160928; }
        dst[i] = f2bf(src[off]);
    }
}

// ---------------------------------------------------------------------------
// GEMM: out[M,N] = epilogue(A[M,K(lda)] @ Bw[N,K]^T + bias[N])
// 128x128x64 tile, 4 waves, 2 K-halves x 16 MFMA (16x16x32 bf16).
// LDS: XOR-swizzled granules. Slot G (16B) holds tile (row=G>>3,
// col_granule=(G&7)^(row&7)) — global_load_lds forbids padding, so the
// swizzle is applied on the SOURCE address; fragment reads XOR by l15&7
// (lane-constant). 8 consecutive rows span all 32 banks -> conflict-free.
// EPI: 0=bias->bf16; 1=bias+gelu->bf16; 2=bias+resid(TRES)->TOUT;
//      3=bias->bf16 with qkv kv-interleave remap (k,v u16 pairs).
// ---------------------------------------------------------------------------
#define BM 128
#define BN 128
#define BK 64

template <int EPI, typename TRES, typename TOUT>
__global__ __launch_bounds__(256) void gemm_nt(
    const u16* __restrict__ A, int lda,
    const u16* __restrict__ Bw,
    const u16* __restrict__ bias,
    const void* __restrict__ resid,
    void* __restrict__ outv,
    int M, int N, int K)
{
    __shared__ alignas(16) u16 As[BM * BK];   // 16 KB
    __shared__ alignas(16) u16 Bs[BN * BK];   // 16 KB

    const int tid  = (int)threadIdx.x;
    const int wid  = tid >> 6;
    const int lane = tid & 63;
    const int l15  = lane & 15;
    const int quad = lane >> 4;
    const int m0   = (int)blockIdx.y * BM;
    const int n0   = (int)blockIdx.x * BN;
    const int wm   = (wid & 1) * 64;
    const int wn   = (wid >> 1) * 64;

    const f32x4 zero4 = {0.f, 0.f, 0.f, 0.f};
    f32x4 acc[4][4];
#pragma unroll
    for (int i = 0; i < 4; i++)
#pragma unroll
        for (int j = 0; j < 4; j++) acc[i][j] = zero4;

    // staging: thread t, group q -> LDS slot G = q*256 + t.
    // tile row r = q*32 + (t>>3); source col granule = (t&7) ^ (r&7) = (t&7)^((t>>3)&7)
    const int srow = tid >> 3;                         // 0..31
    const int scol = (((tid & 7) ^ (srow & 7))) * 8;   // swizzled source col (u16)
    const u16* pa = A + (size_t)(m0 + srow) * lda + scol;
    int brow[4];
#pragma unroll
    for (int q = 0; q < 4; q++) {
        int r = n0 + srow + q * 32;
        brow[q] = (r > N - 1) ? (N - 1) : r;
    }

    const int swz = l15 & 7;  // fragment-row & 7, lane-constant

    for (int k0 = 0; k0 < K; k0 += BK) {
        __syncthreads();
#pragma unroll
        for (int q = 0; q < 4; q++) {
            gl16(pa + (size_t)(q * 32) * lda + k0, As + (size_t)(q * 256 + wid * 64) * 8);
            gl16(Bw + (size_t)brow[q] * K + scol + k0, Bs + (size_t)(q * 256 + wid * 64) * 8);
        }
        __syncthreads();

#pragma unroll
        for (int half = 0; half < 2; half++) {
            const int cg8 = ((half * 4) ^ swz);        // quad folded below
            bf16x8 af[4], bfr[4];
#pragma unroll
            for (int i = 0; i < 4; i++)
                af[i] = *(const bf16x8*)(As + (wm + i * 16 + l15) * BK + (((half * 4 + quad) ^ swz) * 8));
#pragma unroll
            for (int j = 0; j < 4; j++)
                bfr[j] = *(const bf16x8*)(Bs + (wn + j * 16 + l15) * BK + (((half * 4 + quad) ^ swz) * 8));
            (void)cg8;
#pragma unroll
            for (int i = 0; i < 4; i++)
#pragma unroll
                for (int j = 0; j < 4; j++)
                    acc[i][j] = __builtin_amdgcn_mfma_f32_16x16x32_bf16(af[i], bfr[j], acc[i][j], 0, 0, 0);
        }
    }

    // epilogue: reg r of acc[i][j] -> C[m0+wm+i*16+quad*4+r][n0+wn+j*16+l15]
#pragma unroll
    for (int j = 0; j < 4; j++) {
        int ncol = n0 + wn + j * 16 + l15;
        if (ncol >= N) continue;
        float bb = b2f(bias[ncol]);
#pragma unroll
        for (int i = 0; i < 4; i++) {
            int mbase = m0 + wm + i * 16 + quad * 4;
#pragma unroll
            for (int r = 0; r < 4; r++) {
                int m = mbase + r;
                float v = acc[i][j][r] + bb;
                if (EPI == 0) {
                    ((u16*)outv)[(size_t)m * N + ncol] = f2bf(v);
                } else if (EPI == 1) {
                    float g = 0.5f * v * (1.0f + erff(v * 0.70710678118654752f));
                    ((u16*)outv)[(size_t)m * N + ncol] = f2bf(g);
                } else if (EPI == 2) {
                    size_t idx = (size_t)m * N + ncol;
                    float res = (sizeof(TRES) == 4) ? ((const float*)resid)[idx]
                                                    : b2f(((const u16*)resid)[idx]);
                    float o = v + res;
                    if (sizeof(TOUT) == 4) ((float*)outv)[idx] = o;
                    else                   ((u16*)outv)[idx]   = f2bf(o);
                } else {
                    // qkv with kv interleave: q cols as-is; k col d -> 768+2d;
                    // v col d -> 768+2d+1 (u16 units within the 2304-col row).
                    int oc = (ncol < 768) ? ncol
                           : (ncol < 1536) ? (768 + ((ncol - 768) << 1))
                                           : (768 + ((ncol - 1536) << 1) + 1);
                    ((u16*)outv)[(size_t)m * 2304 + oc] = f2bf(v);
                }
            }
        }
    }
}

// ---------------------------------------------------------------------------
// LayerNorm over last dim (768). One block per row. Output bf16.
// ---------------------------------------------------------------------------
template <typename TIN>
__global__ __launch_bounds__(256) void layernorm_k(
    const void* __restrict__ xin,
    const u16* __restrict__ w,
    const u16* __restrict__ bb,
    u16* __restrict__ out)
{
    const int row = (int)blockIdx.x;
    const int tid = (int)threadIdx.x;
    float v[3];
    float s = 0.f, s2 = 0.f;
#pragma unroll
    for (int i = 0; i < 3; i++) {
        int c = tid + i * 256;
        float t = (sizeof(TIN) == 4) ? ((const float*)xin)[(size_t)row * C_ + c]
                                     : b2f(((const u16*)xin)[(size_t)row * C_ + c]);
        v[i] = t; s += t; s2 += t * t;
    }
#pragma unroll
    for (int o = 32; o > 0; o >>= 1) { s += __shfl_xor(s, o); s2 += __shfl_xor(s2, o); }
    __shared__ float red[8];
    const int wid = tid >> 6, lane = tid & 63;
    if (lane == 0) { red[wid] = s; red[4 + wid] = s2; }
    __syncthreads();
    s  = red[0] + red[1] + red[2] + red[3];
    s2 = red[4] + red[5] + red[6] + red[7];
    const float mean = s * (1.0f / C_);
    float var = s2 * (1.0f / C_) - mean * mean;
    const float rstd = rsqrtf(var + 1e-5f);
#pragma unroll
    for (int i = 0; i < 3; i++) {
        int c = tid + i * 256;
        float o_ = (v[i] - mean) * rstd * b2f(w[c]) + b2f(bb[c]);
        out[(size_t)row * C_ + c] = f2bf(o_);
    }
}

// ---------------------------------------------------------------------------
// Deformable sampling + attention. One wave per (b,h,n); lane = channel.
// Phase 1: uniform SALU computes all 16 corner (address, weight) pairs,
//          invalid corners get clamped address + weight 0 (branch-free).
// Phase 2: 16 unconditional global_load_dword issued back-to-back (MLP=16).
// Phase 3: FMA consume, wave-reduce logits, softmax, output.
// ---------------------------------------------------------------------------
__global__ __launch_bounds__(256) void deform_attn(
    const u16* __restrict__ qkv,
    const u16* __restrict__ off,
    const float* __restrict__ refp,
    u16* __restrict__ out)
{
    const int tid  = (int)threadIdx.x;
    const int wid  = tid >> 6;
    const int lane = tid & 63;
    const int wav  = (int)blockIdx.x * 4 + wid;      // 0 .. B*N*HEADS-1
    const int h    = ui(wav % HEADS_);
    const int bn   = ui(wav / HEADS_);               // b*N + n
    const int b    = bn >> 12;

    const float qd = b2f(qkv[(size_t)bn * 2304 + h * HD_ + lane]);
    const float rx = uf(refp[(size_t)bn * 2 + 0]);
    const float ry = uf(refp[(size_t)bn * 2 + 1]);

    const ushort8 ov = *(const ushort8*)(off + (size_t)bn * 96 + h * (PTS_ * 2));

    const u32* q32 = (const u32*)qkv;
    const int ibase = (b << 12);                     // b*N
    const int cbase = 384 + h * (HD_ / 2) * 2 + lane; // u32 idx in row: 384 + h*64 + lane? see below

    // row layout in u32: [0,384) = q pairs (unused here), [384,1152) = kv
    // interleaved: u32 index 384 + d  holds (k[d] | v[d]<<16), d = h*64+lane
    const int cidx = 384 + h * HD_ + lane;
    (void)cbase;

    float wgt[16];
    int   base[16];                                   // uniform u32-row offsets
#pragma unroll
    for (int p = 0; p < PTS_; p++) {
        const float ox = uf(b2f(ov[p * 2 + 0]));
        const float oy = uf(b2f(ov[p * 2 + 1]));
        float px = rx * (float)WW_ + ox - 0.5f;
        float py = ry * (float)HH_ + oy - 0.5f;
        px = fminf(fmaxf(px, -8.f), 72.f);           // NaN/garbage-proof
        py = fminf(fmaxf(py, -8.f), 72.f);
        const float x0f = floorf(px), y0f = floorf(py);
        const int x0 = ui((int)x0f), y0 = ui((int)y0f);
        const float wx = uf(px - x0f), wy = uf(py - y0f);
        const float wxy[4] = { (1.f - wx) * (1.f - wy), wx * (1.f - wy),
                               (1.f - wx) * wy,         wx * wy };
#pragma unroll
        for (int c = 0; c < 4; c++) {
            const int xi = x0 + (c & 1);
            const int yi = y0 + (c >> 1);
            const bool valid = (xi >= 0) & (xi < WW_) & (yi >= 0) & (yi < HH_);
            const int xc = min(max(xi, 0), WW_ - 1);
            const int yc = min(max(yi, 0), HH_ - 1);
            wgt[p * 4 + c]  = valid ? wxy[c] : 0.f;
            base[p * 4 + c] = ui((ibase + yc * WW_ + xc) * 1152);
        }
    }

    // 16 independent loads — maximal per-wave MLP
    u32 kv[16];
#pragma unroll
    for (int t = 0; t < 16; t++) kv[t] = q32[(size_t)base[t] + cidx];

    float logit[PTS_], svd[PTS_];
#pragma unroll
    for (int p = 0; p < PTS_; p++) {
        float sk = 0.f, sv = 0.f;
#pragma unroll
        for (int c = 0; c < 4; c++) {
            const u32 x = kv[p * 4 + c];
            const float w = wgt[p * 4 + c];
            sk = fmaf(w, __int_as_float((int)(x << 16)), sk);
            sv = fmaf(w, __int_as_float((int)(x & 0xffff0000u)), sv);
        }
        logit[p] = qd * sk;
        svd[p]   = sv;
    }
#pragma unroll
    for (int p = 0; p < PTS_; p++)
#pragma unroll
        for (int o = 32; o > 0; o >>= 1) logit[p] += __shfl_xor(logit[p], o);

    const float scale = 0.125f;  // HD^-0.5
    float l0 = logit[0] * scale, l1 = logit[1] * scale, l2 = logit[2] * scale, l3 = logit[3] * scale;
    float mx = fmaxf(fmaxf(l0, l1), fmaxf(l2, l3));
    float e0 = __expf(l0 - mx), e1 = __expf(l1 - mx), e2 = __expf(l2 - mx), e3 = __expf(l3 - mx);
    float Z = e0 + e1 + e2 + e3;
    float od = (e0 * svd[0] + e1 * svd[1] + e2 * svd[2] + e3 * svd[3]) / Z;
    out[(size_t)bn * C_ + h * HD_ + lane] = f2bf(od);
}

// ---------------------------------------------------------------------------
extern "C" void kernel_launch(void* const* d_in, const int* in_sizes, int n_in,
                              void* d_out, int out_size, void* d_ws, size_t ws_size,
                              hipStream_t stream)
{
    const float* x     = (const float*)d_in[0];
    const float* refp  = (const float*)d_in[1];
    const float* n1w   = (const float*)d_in[2];
    const float* n1b   = (const float*)d_in[3];
    const float* qkvw  = (const float*)d_in[4];
    const float* qkvb  = (const float*)d_in[5];
    const float* offw  = (const float*)d_in[6];
    const float* offb  = (const float*)d_in[7];
    const float* projw = (const float*)d_in[8];
    const float* projb = (const float*)d_in[9];
    const float* n2w   = (const float*)d_in[10];
    const float* n2b   = (const float*)d_in[11];
    const float* fc1w  = (const float*)d_in[12];
    const float* fc1b  = (const float*)d_in[13];
    const float* fc2w  = (const float*)d_in[14];
    const float* fc2b  = (const float*)d_in[15];
    (void)in_sizes; (void)n_in; (void)out_size; (void)ws_size;

    const int M = B_ * N_;  // 16384

    // Workspace layout — peak 118,132,416 B:
    //   A [0,         25165824): h (LN1) -> aout -> h2 (LN2)
    //   B [25165824, 100663296): qkv (kv pre-interleaved by GEMM epilogue)
    //                            -> x1 [25.1M,50.3M) + mbuf [50.3M,100.66M)
    //   C [100663296,103809024): offo
    //   D [103809024,118132416): bf16 weights/biases
    char* ws = (char*)d_ws;
    u16* h    = (u16*)(ws);
    u16* aout = (u16*)(ws);
    u16* h2   = (u16*)(ws);
    u16* qkv  = (u16*)(ws + 25165824);
    u16* x1   = (u16*)(ws + 25165824);
    u16* mbuf = (u16*)(ws + 50331648);
    u16* offo = (u16*)(ws + 100663296);
    u16* cw   = (u16*)(ws + 103809024);

    u16* qkvw_c = cw +       0;
    u16* projw_c= cw + 1769472;
    u16* fc1w_c = cw + 2359296;
    u16* fc2w_c = cw + 4718592;
    u16* offw_c = cw + 7077888;
    u16* qkvb_c = cw + 7151616;
    u16* projb_c= cw + 7153920;
    u16* fc1b_c = cw + 7154688;
    u16* fc2b_c = cw + 7157760;
    u16* offb_c = cw + 7158528;
    u16* n1w_c  = cw + 7158624;
    u16* n1b_c  = cw + 7159392;
    u16* n2w_c  = cw + 7160160;
    u16* n2b_c  = cw + 7160928;

    dim3 blk(256);
    const int CH = 8192;                  // MLP row-chunk

    convert_k<<<dim3(2048), blk, 0, stream>>>(qkvw, projw, fc1w, fc2w, offw,
        qkvb, projb, fc1b, fc2b, offb, n1w, n1b, n2w, n2b, cw);
    // 1) LN1: x -> h
    layernorm_k<float><<<dim3(M), blk, 0, stream>>>(x, n1w_c, n1b_c, h);
    // 2) qkv = h @ qkv_w^T + qkv_b, kv interleaved in epilogue
    gemm_nt<3, u16, u16><<<dim3((3 * C_) / BN, M / BM), blk, 0, stream>>>(
        h, C_, qkvw_c, qkvb_c, nullptr, qkv, M, 3 * C_, C_);
    // 3) off = q @ off_w^T + off_b   (q = first 768 cols, lda=2304)
    gemm_nt<0, u16, u16><<<dim3(1, M / BM), blk, 0, stream>>>(
        qkv, 2304, offw_c, offb_c, nullptr, offo, M, HEADS_ * PTS_ * 2, C_);
    // 4) sampling + attention -> aout (h dead)
    deform_attn<<<dim3(M * HEADS_ / 4), blk, 0, stream>>>(qkv, offo, refp, aout);
    // 5) x1 = x + aout @ proj_w^T + proj_b (qkv dead -> x1)
    gemm_nt<2, float, u16><<<dim3(C_ / BN, M / BM), blk, 0, stream>>>(
        aout, C_, projw_c, projb_c, x, x1, M, C_, C_);
    // 6) LN2: x1 -> h2 (aout dead)
    layernorm_k<u16><<<dim3(M), blk, 0, stream>>>(x1, n2w_c, n2b_c, h2);
    // 7/8) MLP in two 8192-row chunks
    for (int c = 0; c < 2; c++) {
        const u16* h2c = h2 + (size_t)c * CH * C_;
        const u16* x1c = x1 + (size_t)c * CH * C_;
        float* outc = (float*)d_out + (size_t)c * CH * C_;
        gemm_nt<1, u16, u16><<<dim3(HID_ / BN, CH / BM), blk, 0, stream>>>(
            h2c, C_, fc1w_c, fc1b_c, nullptr, mbuf, CH, HID_, C_);
        gemm_nt<2, u16, float><<<dim3(C_ / BN, CH / BM), blk, 0, stream>>>(
            mbuf, HID_, fc2w_c, fc2b_c, x1c, outc, CH, C_, HID_);
    }
}